// Round 4
// baseline (3910.786 us; speedup 1.0000x reference)
//
#include <hip/hip_runtime.h>

typedef unsigned short ushort_t;
typedef __attribute__((ext_vector_type(8))) short bf16x8;
typedef __attribute__((ext_vector_type(4))) float f32x4;

#define BB 32
#define TT 64
#define HH 512
#define G4H 2048

__device__ __forceinline__ ushort_t f2bf(float f) {
    unsigned int u = __float_as_uint(f);
    unsigned int r = (u + 0x7fffu + ((u >> 16) & 1u)) >> 16;
    return (ushort_t)r;
}
__device__ __forceinline__ void split_bf(float f, ushort_t& hi, ushort_t& lo) {
    unsigned int hu = f2bf(f);
    hi = (ushort_t)hu;
    float hf = __uint_as_float(hu << 16);
    lo = f2bf(f - hf);
}
__device__ __forceinline__ float sigf(float x) { return 1.f / (1.f + __expf(-x)); }
__device__ __forceinline__ float tanh_(float x) {
    float e = __expf(2.f * x);
    return 1.f - 2.f / (e + 1.f);
}

// coherent (cross-XCD) 64B load: 4x dwordx4 with sc0 sc1, single waitcnt
__device__ __forceinline__ void ld16_sc(const float* p, f32x4& a, f32x4& b, f32x4& c, f32x4& d) {
    asm volatile(
        "global_load_dwordx4 %0, %4, off sc0 sc1\n\t"
        "global_load_dwordx4 %1, %5, off sc0 sc1\n\t"
        "global_load_dwordx4 %2, %6, off sc0 sc1\n\t"
        "global_load_dwordx4 %3, %7, off sc0 sc1\n\t"
        "s_waitcnt vmcnt(0)"
        : "=&v"(a), "=&v"(b), "=&v"(c), "=&v"(d)
        : "v"(p), "v"(p + 4), "v"(p + 8), "v"(p + 12)
        : "memory");
}
// coherent 4B store
__device__ __forceinline__ void st1_sc(float* p, float v) {
    asm volatile("global_store_dword %0, %1, off sc0 sc1" :: "v"(p), "v"(v) : "memory");
}

// ---------------- zero init (barriers + zeros vector) ----------------
__global__ void zero_init(float* zeros, int* bars) {
    int t = threadIdx.x;
    if (t < 128) ((float4*)zeros)[t] = make_float4(0.f, 0.f, 0.f, 0.f); // 512 floats
    ((int4*)bars)[t] = make_int4(0, 0, 0, 0); // 1024 ints
}

// ---------------- embedding gather ----------------
__global__ void gather_rows(const int* __restrict__ idx, const float* __restrict__ emb,
                            float* __restrict__ out) {
    int row = blockIdx.x;      // 2048 rows
    int t = threadIdx.x;       // 64 threads
    int id = idx[row];
    float4 v = *(const float4*)(emb + (size_t)id * 256 + t * 4);
    *(float4*)(out + (size_t)row * 256 + t * 4) = v;
}

// ---------------- generic fp32 GEMM: C[M,N] = act(A[M,K] * B[N,K]^T + bias) ----------------
// mode 0: fp32 out, no act. mode 2: tanh then bf16 out.
__global__ __launch_bounds__(256) void gemm_f32(
    const float* __restrict__ A, int lda,
    const float* __restrict__ B, int ldb,
    const float* __restrict__ bias,
    void* __restrict__ Cv, int ldc,
    int M, int N, int K, int mode)
{
    __shared__ float As[16 * 68];
    __shared__ float Bs[16 * 68];
    const int tid = threadIdx.x;
    const int bm = blockIdx.y * 64, bn = blockIdx.x * 64;
    const int lr = tid >> 2, lk = (tid & 3) << 2;
    const int tr = (tid >> 4) << 2, tc = (tid & 15) << 2;
    float acc[4][4] = {};
    const int arow = bm + lr, brow = bn + lr;
    const bool aval = arow < M, bval = brow < N;
    const float* Ap = A + (size_t)arow * lda + lk;
    const float* Bp = B + (size_t)brow * ldb + lk;

    for (int k0 = 0; k0 < K; k0 += 16) {
        float4 av = make_float4(0.f, 0.f, 0.f, 0.f);
        float4 bv = make_float4(0.f, 0.f, 0.f, 0.f);
        if (aval) av = *(const float4*)(Ap + k0);
        if (bval) bv = *(const float4*)(Bp + k0);
        As[(lk + 0) * 68 + lr] = av.x; As[(lk + 1) * 68 + lr] = av.y;
        As[(lk + 2) * 68 + lr] = av.z; As[(lk + 3) * 68 + lr] = av.w;
        Bs[(lk + 0) * 68 + lr] = bv.x; Bs[(lk + 1) * 68 + lr] = bv.y;
        Bs[(lk + 2) * 68 + lr] = bv.z; Bs[(lk + 3) * 68 + lr] = bv.w;
        __syncthreads();
        #pragma unroll
        for (int kk = 0; kk < 16; kk++) {
            float4 a = *(const float4*)&As[kk * 68 + tr];
            float4 b = *(const float4*)&Bs[kk * 68 + tc];
            float ar[4] = {a.x, a.y, a.z, a.w};
            float br[4] = {b.x, b.y, b.z, b.w};
            #pragma unroll
            for (int i = 0; i < 4; i++)
                #pragma unroll
                for (int j = 0; j < 4; j++)
                    acc[i][j] = fmaf(ar[i], br[j], acc[i][j]);
        }
        __syncthreads();
    }
    #pragma unroll
    for (int i = 0; i < 4; i++) {
        int m = bm + tr + i;
        if (m >= M) continue;
        #pragma unroll
        for (int j = 0; j < 4; j++) {
            int n = bn + tc + j;
            if (n >= N) continue;
            float v = acc[i][j] + (bias ? bias[n] : 0.f);
            if (mode == 0) {
                ((float*)Cv)[(size_t)m * ldc + n] = v;
            } else {
                ((ushort_t*)Cv)[(size_t)m * ldc + n] = f2bf(tanh_(v));
            }
        }
    }
}

// ---------------- context mean ----------------
__global__ void mean_ctx(const float* __restrict__ e1, float* __restrict__ ctx) {
    int g = blockIdx.x * 256 + threadIdx.x; // 16384
    int b = g >> 9, u = g & 511;
    float s = 0.f;
    #pragma unroll 8
    for (int t = 0; t < TT; t++) s += e1[((size_t)b * TT + t) * HH + u];
    ctx[g] = s * (1.f / 64.f);
}

// ---------------- LSTM scan v4: MFMA recurrence ----------------
// 256 blocks = 4 batch-groups (8 batches) x 64 unit-blocks (8 h-units = 32 gate rows).
// Whh held in VGPRs as bf16 hi/lo split (3-term MFMA ~ fp32 accuracy).
// h staged per step as bf16 hi/lo in LDS (16-row tile, rows 8..15 zero).
// Waves: ni = wave&1 (N-half of 32 gate rows), kh = wave>>1 (K-half of 512).
// h exchanged coherently through `out`; per-group 64-block relaxed barrier.
__global__ __launch_bounds__(256) void lstm_scan(
    const float* __restrict__ gatesX,  // [B*T][4H] precomputed x-projection (incl bias)
    const float* __restrict__ ctxAdd,  // [B][4H] or null (decoder layer0 context term)
    const float* __restrict__ Whh,     // [4H][H]
    const float* __restrict__ h0, int h0_stride,
    const float* __restrict__ c0, int c0_stride,
    float* __restrict__ out,           // [B*T][H] (also the coherent exchange buffer)
    float* __restrict__ cT,            // [B][H] or null
    int* __restrict__ bar)             // 63 steps x 4 groups ints, pre-zeroed
{
    __shared__ ushort_t ah[16 * 520];   // h hi, [batch 0..15][k 0..511], rows 8..15 zero
    __shared__ ushort_t al[16 * 520];   // h lo
    __shared__ float glds[2][16][33];   // partial gate sums [khalf][m][n]
    const int tid = threadIdx.x;
    const int bg = blockIdx.x >> 6;     // batch group 0..3
    const int ub = blockIdx.x & 63;     // unit block 0..63
    const int u0 = ub * 8;
    const int lane = tid & 63, wave = tid >> 6;
    const int ni = wave & 1, kh = wave >> 1;
    const int lr = lane & 15, ls = lane >> 4;

    // zero A rows 8..15 once (read as zero-padding by MFMA)
    for (int i = tid; i < 8 * 520; i += 256) { ah[8 * 520 + i] = 0; al[8 * 520 + i] = 0; }

    // stationary Whh fragments -> registers (bf16 hi/lo split)
    bf16x8 b_hi[8], b_lo[8];
    {
        const int n = ni * 16 + lr;                       // output col 0..31
        const int grow = (n >> 3) * HH + u0 + (n & 7);    // gate*H + unit
        const float* wr = Whh + (size_t)grow * HH + kh * 256 + ls * 8;
        #pragma unroll
        for (int kk = 0; kk < 8; kk++) {
            float f[8];
            *(f32x4*)&f[0] = *(const f32x4*)(wr + kk * 32);
            *(f32x4*)&f[4] = *(const f32x4*)(wr + kk * 32 + 4);
            bf16x8 hv, lv;
            #pragma unroll
            for (int j = 0; j < 8; j++) {
                ushort_t hu, lu; split_bf(f[j], hu, lu);
                hv[j] = (short)hu; lv[j] = (short)lu;
            }
            b_hi[kk] = hv; b_lo[kk] = lv;
        }
    }

    // pointwise-thread state (tid<64): c register, gatesX pipeline, ctx term
    const int b2 = tid >> 3, uu = tid & 7;
    const int bglob2 = bg * 8 + b2;
    float creg = 0.f;
    float gx_cur[4] = {0.f, 0.f, 0.f, 0.f}, gx_nxt[4] = {0.f, 0.f, 0.f, 0.f};
    float xctx4[4] = {0.f, 0.f, 0.f, 0.f};
    if (tid < 64) {
        creg = c0[(size_t)bglob2 * c0_stride + u0 + uu];
        #pragma unroll
        for (int g = 0; g < 4; g++) {
            gx_cur[g] = gatesX[(size_t)bglob2 * TT * G4H + g * HH + u0 + uu];
            if (ctxAdd) xctx4[g] = ctxAdd[(size_t)bglob2 * G4H + g * HH + u0 + uu];
        }
    }

    const int srow = tid >> 5;          // staging: batch row 0..7
    const int scol = (tid & 31) * 16;   // 16-float chunk

    for (int t = 0; t < TT; t++) {
        // ---- stage h_prev (8 batches x 512 f32) -> bf16 hi/lo LDS ----
        f32x4 v0, v1, v2, v3;
        if (t == 0) {
            const float* hs = h0 + (size_t)(bg * 8 + srow) * h0_stride + scol;
            v0 = *(const f32x4*)hs;       v1 = *(const f32x4*)(hs + 4);
            v2 = *(const f32x4*)(hs + 8); v3 = *(const f32x4*)(hs + 12);
        } else {
            const float* hs = out + ((size_t)(bg * 8 + srow) * TT + (t - 1)) * HH + scol;
            ld16_sc(hs, v0, v1, v2, v3);
        }
        // gatesX prefetch for NEXT step (issued after h loads, before LDS writes)
        __builtin_amdgcn_sched_barrier(0);
        if (tid < 64) {
            int tn = (t + 1 < TT) ? t + 1 : t;
            #pragma unroll
            for (int g = 0; g < 4; g++)
                gx_nxt[g] = gatesX[((size_t)bglob2 * TT + tn) * G4H + g * HH + u0 + uu];
        }
        __builtin_amdgcn_sched_barrier(0);
        {
            float hv[16];
            *(f32x4*)&hv[0]  = v0; *(f32x4*)&hv[4]  = v1;
            *(f32x4*)&hv[8]  = v2; *(f32x4*)&hv[12] = v3;
            bf16x8 h0v, h1v, l0v, l1v;
            #pragma unroll
            for (int j = 0; j < 8; j++) {
                ushort_t hu, lu; split_bf(hv[j], hu, lu);
                h0v[j] = (short)hu; l0v[j] = (short)lu;
            }
            #pragma unroll
            for (int j = 0; j < 8; j++) {
                ushort_t hu, lu; split_bf(hv[8 + j], hu, lu);
                h1v[j] = (short)hu; l1v[j] = (short)lu;
            }
            ushort_t* ap = &ah[srow * 520 + scol];
            ushort_t* lp = &al[srow * 520 + scol];
            *(bf16x8*)ap = h0v; *(bf16x8*)(ap + 8) = h1v;
            *(bf16x8*)lp = l0v; *(bf16x8*)(lp + 8) = l1v;
        }
        __syncthreads();
        // ---- recurrent GEMM: 24 MFMA per wave (hi*hi + lo*hi + hi*lo) ----
        {
            f32x4 acc = {0.f, 0.f, 0.f, 0.f};
            const int abase = lr * 520 + kh * 256 + ls * 8;
            #pragma unroll
            for (int kk = 0; kk < 8; kk++) {
                bf16x8 ahf = *(const bf16x8*)&ah[abase + kk * 32];
                bf16x8 alf = *(const bf16x8*)&al[abase + kk * 32];
                acc = __builtin_amdgcn_mfma_f32_16x16x32_bf16(ahf, b_hi[kk], acc, 0, 0, 0);
                acc = __builtin_amdgcn_mfma_f32_16x16x32_bf16(alf, b_hi[kk], acc, 0, 0, 0);
                acc = __builtin_amdgcn_mfma_f32_16x16x32_bf16(ahf, b_lo[kk], acc, 0, 0, 0);
            }
            #pragma unroll
            for (int q = 0; q < 4; q++)
                glds[kh][ls * 4 + q][ni * 16 + lr] = acc[q];
        }
        __syncthreads();
        // ---- pointwise gates + coherent h publish ----
        if (tid < 64) {
            float pre[4];
            #pragma unroll
            for (int g = 0; g < 4; g++)
                pre[g] = glds[0][b2][g * 8 + uu] + glds[1][b2][g * 8 + uu]
                       + gx_cur[g] + xctx4[g];
            float c = sigf(pre[1]) * creg + sigf(pre[0]) * tanh_(pre[2]);
            float h = sigf(pre[3]) * tanh_(c);
            creg = c;
            out[((size_t)bglob2 * TT + t) * HH + u0 + uu] = h; // plain store path unused by scan readers
            st1_sc(out + ((size_t)bglob2 * TT + t) * HH + u0 + uu, h);
            if (cT && t == TT - 1) cT[(size_t)bglob2 * HH + u0 + uu] = c;
        }
        if (t + 1 < TT) {
            // own coherent stores acked, then relaxed group barrier
            asm volatile("s_waitcnt vmcnt(0)" ::: "memory");
            __syncthreads();
            if (tid == 0) {
                int* bp = bar + t * 4 + bg;
                __hip_atomic_fetch_add(bp, 1, __ATOMIC_RELAXED, __HIP_MEMORY_SCOPE_AGENT);
                while (__hip_atomic_load(bp, __ATOMIC_RELAXED, __HIP_MEMORY_SCOPE_AGENT) < 64)
                    __builtin_amdgcn_s_sleep(1);
            }
            __syncthreads();
        }
        #pragma unroll
        for (int g = 0; g < 4; g++) gx_cur[g] = gx_nxt[g];
    }
}

// ---------------- final projection: bf16 MFMA GEMM, C = A*B^T + bias ----------------
// A: hid bf16 [M][K]. B: W2 fp32 [N][K] (converted to bf16 during staging). C fp32.
__global__ __launch_bounds__(256) void gemm_bf16(
    const ushort_t* __restrict__ A,
    const float* __restrict__ B,
    const float* __restrict__ bias,
    float* __restrict__ C, int M, int N, int K)
{
    __shared__ ushort_t As[128 * 72];
    __shared__ ushort_t Bs[128 * 72];
    const int tid = threadIdx.x;
    const int bm = blockIdx.x * 128, bn = blockIdx.y * 128;
    const int lane = tid & 63, wave = tid >> 6;
    const int wm = (wave & 1) * 64, wn = (wave >> 1) * 64;
    const int lr = lane & 15, lk = (lane >> 4) * 8;
    const int srow = tid >> 3, sch = tid & 7;
    f32x4 acc[4][4] = {};

    for (int k0 = 0; k0 < K; k0 += 64) {
        #pragma unroll
        for (int rr = 0; rr < 4; rr++) {
            int row = srow + rr * 32;
            const ushort_t* as = A + (size_t)(bm + row) * K + k0 + sch * 8;
            *(int4*)&As[row * 72 + sch * 8] = *(const int4*)as;
            const float* bs = B + (size_t)(bn + row) * K + k0 + sch * 8;
            float4 f0 = *(const float4*)bs;
            float4 f1 = *(const float4*)(bs + 4);
            int4 pk;
            pk.x = (int)f2bf(f0.x) | ((int)f2bf(f0.y) << 16);
            pk.y = (int)f2bf(f0.z) | ((int)f2bf(f0.w) << 16);
            pk.z = (int)f2bf(f1.x) | ((int)f2bf(f1.y) << 16);
            pk.w = (int)f2bf(f1.z) | ((int)f2bf(f1.w) << 16);
            *(int4*)&Bs[row * 72 + sch * 8] = pk;
        }
        __syncthreads();
        #pragma unroll
        for (int k2 = 0; k2 < 64; k2 += 32) {
            bf16x8 a[4], bfr[4];
            #pragma unroll
            for (int i = 0; i < 4; i++)
                a[i] = *(const bf16x8*)&As[(wm + i * 16 + lr) * 72 + k2 + lk];
            #pragma unroll
            for (int j = 0; j < 4; j++)
                bfr[j] = *(const bf16x8*)&Bs[(wn + j * 16 + lr) * 72 + k2 + lk];
            #pragma unroll
            for (int i = 0; i < 4; i++)
                #pragma unroll
                for (int j = 0; j < 4; j++)
                    acc[i][j] = __builtin_amdgcn_mfma_f32_16x16x32_bf16(a[i], bfr[j], acc[i][j], 0, 0, 0);
        }
        __syncthreads();
    }
    const int r0 = (lane >> 4) * 4;
    #pragma unroll
    for (int j = 0; j < 4; j++) {
        int col = bn + wn + j * 16 + lr;
        float bv = bias[col];
        #pragma unroll
        for (int i = 0; i < 4; i++) {
            int row = bm + wm + i * 16 + r0;
            #pragma unroll
            for (int q = 0; q < 4; q++)
                C[(size_t)(row + q) * N + col] = acc[i][j][q] + bv;
        }
    }
}

extern "C" void kernel_launch(void* const* d_in, const int* in_sizes, int n_in,
                              void* d_out, int out_size, void* d_ws, size_t ws_size,
                              hipStream_t stream) {
    const int*   src      = (const int*)d_in[0];
    const int*   tgt      = (const int*)d_in[1];
    const float* enc_emb  = (const float*)d_in[2];
    const float* dec_emb  = (const float*)d_in[3];
    const float* eWih0    = (const float*)d_in[4];
    const float* eWhh0    = (const float*)d_in[5];
    const float* eb0      = (const float*)d_in[6];
    const float* eWih1    = (const float*)d_in[7];
    const float* eWhh1    = (const float*)d_in[8];
    const float* eb1      = (const float*)d_in[9];
    const float* dWih0    = (const float*)d_in[10];
    const float* dWhh0    = (const float*)d_in[11];
    const float* db0      = (const float*)d_in[12];
    const float* dWih1    = (const float*)d_in[13];
    const float* dWhh1    = (const float*)d_in[14];
    const float* db1      = (const float*)d_in[15];
    const float* pW1      = (const float*)d_in[16];
    const float* pb1      = (const float*)d_in[17];
    const float* pW2      = (const float*)d_in[18];
    const float* pb2      = (const float*)d_in[19];
    float* out = (float*)d_out;

    // workspace carve (small persistent buffers)
    float* fws   = (float*)d_ws;
    float* zeros = fws;                        // 512 f (padded to 1024)
    int*   bars  = (int*)(fws + 1024);         // 1024 ints (4 layers x 63 steps x 4 groups)
    float* cT0   = fws + 2048;                 // 16384 f
    float* cT1   = cT0 + 16384;
    float* ctx   = cT1 + 16384;
    float* ctxW  = ctx + 16384;                // 65536 f
    ushort_t* hid = (ushort_t*)(ctxW + 65536); // 2048*512 bf16

    // d_out scratch (all dead before final projection writes everything)
    float* G0  = out;                 // 2048*2048 gate buffers
    float* G1  = G0 + 4194304;
    float* G2  = G1 + 4194304;
    float* G3  = G2 + 4194304;
    float* xe  = G3 + 4194304;        // 2048*256
    float* xd  = xe + 524288;
    float* e0  = xd + 524288;         // 2048*512
    float* e1  = e0 + 1048576;
    float* d0  = e1 + 1048576;
    float* d1v = d0 + 1048576;

    zero_init<<<1, 256, 0, stream>>>(zeros, bars);
    gather_rows<<<2048, 64, 0, stream>>>(src, enc_emb, xe);
    gather_rows<<<2048, 64, 0, stream>>>(tgt, dec_emb, xd);

    // encoder layer 0
    gemm_f32<<<dim3(32, 32), 256, 0, stream>>>(xe, 256, eWih0, 256, eb0, G0, 2048, 2048, 2048, 256, 0);
    lstm_scan<<<256, 256, 0, stream>>>(G0, nullptr, eWhh0, zeros, 0, zeros, 0, e0, cT0, bars);
    // encoder layer 1
    gemm_f32<<<dim3(32, 32), 256, 0, stream>>>(e0, 512, eWih1, 512, eb1, G1, 2048, 2048, 2048, 512, 0);
    lstm_scan<<<256, 256, 0, stream>>>(G1, nullptr, eWhh1, zeros, 0, zeros, 0, e1, cT1, bars + 256);
    // context
    mean_ctx<<<64, 256, 0, stream>>>(e1, ctx);
    // decoder layer 0: gates = xd*Wih[:, :256]^T + b + ctx*Wih[:, 256:]^T (added in scan)
    gemm_f32<<<dim3(32, 32), 256, 0, stream>>>(xd, 256, dWih0, 768, db0, G2, 2048, 2048, 2048, 256, 0);
    gemm_f32<<<dim3(32, 1), 256, 0, stream>>>(ctx, 512, dWih0 + 256, 768, nullptr, ctxW, 2048, 32, 2048, 512, 0);
    lstm_scan<<<256, 256, 0, stream>>>(G2, ctxW, dWhh0, e0 + 63 * 512, 64 * 512, cT0, 512, d0, nullptr, bars + 512);
    // decoder layer 1
    gemm_f32<<<dim3(32, 32), 256, 0, stream>>>(d0, 512, dWih1, 512, db1, G3, 2048, 2048, 2048, 512, 0);
    lstm_scan<<<256, 256, 0, stream>>>(G3, nullptr, dWhh1, e1 + 63 * 512, 64 * 512, cT1, 512, d1v, nullptr, bars + 768);
    // projection: hid = tanh(d1*W1^T + b1) stored bf16; logits = hid*W2^T + b2 (MFMA)
    gemm_f32<<<dim3(8, 32), 256, 0, stream>>>(d1v, 512, pW1, 512, pb1, hid, 512, 2048, 512, 512, 2);
    gemm_bf16<<<dim3(16, 250), 256, 0, stream>>>(hid, pW2, pb2, out, 2048, 32000, 512);
}

// Round 5
// 1901.750 us; speedup vs baseline: 2.0564x; 2.0564x over previous
//
#include <hip/hip_runtime.h>

typedef unsigned short ushort_t;
typedef __attribute__((ext_vector_type(8))) short bf16x8;
typedef __attribute__((ext_vector_type(4))) float f32x4;

#define BB 32
#define TT 64
#define HH 512
#define G4H 2048

__device__ __forceinline__ ushort_t f2bf(float f) {
    unsigned int u = __float_as_uint(f);
    unsigned int r = (u + 0x7fffu + ((u >> 16) & 1u)) >> 16;
    return (ushort_t)r;
}
__device__ __forceinline__ float sigf(float x) { return 1.f / (1.f + __expf(-x)); }
__device__ __forceinline__ float tanh_(float x) {
    float e = __expf(2.f * x);
    return 1.f - 2.f / (e + 1.f);
}

// ---------------- zero init (zeros vector for h0/c0) ----------------
__global__ void zero_init(float* zeros) {
    int t = threadIdx.x;
    if (t < 128) ((float4*)zeros)[t] = make_float4(0.f, 0.f, 0.f, 0.f); // 512 floats
}

// ---------------- embedding gather ----------------
__global__ void gather_rows(const int* __restrict__ idx, const float* __restrict__ emb,
                            float* __restrict__ out) {
    int row = blockIdx.x;      // 2048 rows
    int t = threadIdx.x;       // 64 threads
    int id = idx[row];
    float4 v = *(const float4*)(emb + (size_t)id * 256 + t * 4);
    *(float4*)(out + (size_t)row * 256 + t * 4) = v;
}

// ---------------- generic fp32 GEMM: C[M,N] = act(A[M,K] * B[N,K]^T + bias) ----------------
// mode 0: fp32 out, no act. mode 2: tanh then bf16 out.
__global__ __launch_bounds__(256) void gemm_f32(
    const float* __restrict__ A, int lda,
    const float* __restrict__ B, int ldb,
    const float* __restrict__ bias,
    void* __restrict__ Cv, int ldc,
    int M, int N, int K, int mode)
{
    __shared__ float As[16 * 68];
    __shared__ float Bs[16 * 68];
    const int tid = threadIdx.x;
    const int bm = blockIdx.y * 64, bn = blockIdx.x * 64;
    const int lr = tid >> 2, lk = (tid & 3) << 2;
    const int tr = (tid >> 4) << 2, tc = (tid & 15) << 2;
    float acc[4][4] = {};
    const int arow = bm + lr, brow = bn + lr;
    const bool aval = arow < M, bval = brow < N;
    const float* Ap = A + (size_t)arow * lda + lk;
    const float* Bp = B + (size_t)brow * ldb + lk;

    for (int k0 = 0; k0 < K; k0 += 16) {
        float4 av = make_float4(0.f, 0.f, 0.f, 0.f);
        float4 bv = make_float4(0.f, 0.f, 0.f, 0.f);
        if (aval) av = *(const float4*)(Ap + k0);
        if (bval) bv = *(const float4*)(Bp + k0);
        As[(lk + 0) * 68 + lr] = av.x; As[(lk + 1) * 68 + lr] = av.y;
        As[(lk + 2) * 68 + lr] = av.z; As[(lk + 3) * 68 + lr] = av.w;
        Bs[(lk + 0) * 68 + lr] = bv.x; Bs[(lk + 1) * 68 + lr] = bv.y;
        Bs[(lk + 2) * 68 + lr] = bv.z; Bs[(lk + 3) * 68 + lr] = bv.w;
        __syncthreads();
        #pragma unroll
        for (int kk = 0; kk < 16; kk++) {
            float4 a = *(const float4*)&As[kk * 68 + tr];
            float4 b = *(const float4*)&Bs[kk * 68 + tc];
            float ar[4] = {a.x, a.y, a.z, a.w};
            float br[4] = {b.x, b.y, b.z, b.w};
            #pragma unroll
            for (int i = 0; i < 4; i++)
                #pragma unroll
                for (int j = 0; j < 4; j++)
                    acc[i][j] = fmaf(ar[i], br[j], acc[i][j]);
        }
        __syncthreads();
    }
    #pragma unroll
    for (int i = 0; i < 4; i++) {
        int m = bm + tr + i;
        if (m >= M) continue;
        #pragma unroll
        for (int j = 0; j < 4; j++) {
            int n = bn + tc + j;
            if (n >= N) continue;
            float v = acc[i][j] + (bias ? bias[n] : 0.f);
            if (mode == 0) {
                ((float*)Cv)[(size_t)m * ldc + n] = v;
            } else {
                ((ushort_t*)Cv)[(size_t)m * ldc + n] = f2bf(tanh_(v));
            }
        }
    }
}

// ---------------- context mean ----------------
__global__ void mean_ctx(const float* __restrict__ e1, float* __restrict__ ctx) {
    int g = blockIdx.x * 256 + threadIdx.x; // 16384
    int b = g >> 9, u = g & 511;
    float s = 0.f;
    #pragma unroll 8
    for (int t = 0; t < TT; t++) s += e1[((size_t)b * TT + t) * HH + u];
    ctx[g] = s * (1.f / 64.f);
}

// ---------------- LSTM scan v5: tagged-data exchange (no barrier) ----------------
// 256 blocks = 4 batch-groups (8 batches) x 64 unit-blocks (8 h-units = 32 gate rows).
// Producers publish each h as packed (tag<<32 | bits(h)) relaxed agent atomics into
// ring[t][b][u]; consumers poll-load their 16 staging elements until tags match.
// No barrier, no vmcnt drains, no RMW serialization on the critical path.
__global__ __launch_bounds__(256) void lstm_scan(
    const float* __restrict__ gatesX,  // [B*T][4H] precomputed x-projection (incl bias)
    const float* __restrict__ ctxAdd,  // [B][4H] or null (decoder layer0 context term)
    const float* __restrict__ Whh,     // [4H][H]
    const float* __restrict__ h0, int h0_stride,
    const float* __restrict__ c0, int c0_stride,
    float* __restrict__ out,           // [B*T][H] (plain stores; read by later kernels)
    float* __restrict__ cT,            // [B][H] or null
    unsigned long long* __restrict__ ring, // [T][B][H] tagged h exchange
    int tag_base)                      // layer*64; tag for step t = tag_base+t+1
{
    __shared__ float wlds[32 * 516];
    __shared__ float hlds[8 * 516];
    __shared__ float glds[8 * 33];
    __shared__ float clds[64];
    const int tid = threadIdx.x;
    const int bg = blockIdx.x >> 6;        // batch group 0..3
    const int ub = blockIdx.x & 63;        // unit block 0..63
    const int u0 = ub * 8;
    const int bb = (tid >> 3) & 7;         // batch within group (dot role)
    const int rr = (tid >> 6) * 8 + (tid & 7); // row 0..31 (gate = rr>>3 = wave id)
    const int grow = (rr >> 3) * HH + u0 + (rr & 7);
    const int bglob = bg * 8 + bb;

    { // stationary weights -> LDS: row = tid>>3, 64-col chunk = (tid&7)*64
        const int srow = tid >> 3, scol = (tid & 7) * 64;
        const int sg = srow >> 3, su = srow & 7;
        const float* wsrc = Whh + (size_t)(sg * HH + u0 + su) * HH + scol;
        float* wdst = &wlds[srow * 516 + scol];
        #pragma unroll
        for (int j = 0; j < 64; j += 4) *(f32x4*)(wdst + j) = *(const f32x4*)(wsrc + j);
    }
    if (tid < 64) { // c state: (bb2, uu2)
        clds[tid] = c0[(size_t)(bg * 8 + (tid >> 3)) * c0_stride + u0 + (tid & 7)];
    }
    const float xctx = ctxAdd ? ctxAdd[(size_t)bglob * G4H + grow] : 0.f;
    const int hrow = tid >> 5;             // staging role: batch row 0..7
    const int hc0 = tid & 31;              // lane within row
    const float* gxp = gatesX + (size_t)bglob * TT * G4H + grow;
    float gx_cur = gxp[0];
    float gx_nxt;

    { // stage h0 (plain loads) -> hlds
        const float* hs = h0 + (size_t)(bg * 8 + hrow) * h0_stride;
        float* hd = &hlds[hrow * 516 + hc0];
        #pragma unroll
        for (int j = 0; j < 16; j++) hd[32 * j] = hs[hc0 + 32 * j];
    }

    for (int t = 0; t < TT; t++) {
        __syncthreads();   // hlds (and prev glds consumption) ready
        // prefetch gatesX for NEXT step: full dot of slack to complete
        {
            int tn = (t + 1 < TT) ? t + 1 : t;
            gx_nxt = gxp[(size_t)tn * G4H];
        }
        // dot(h_prev[bb,:], Whh[grow,:]) -- broadcast-friendly LDS reads
        f32x4 s = {0.f, 0.f, 0.f, 0.f};
        const float* hp = &hlds[bb * 516];
        const float* wp = &wlds[rr * 516];
        #pragma unroll 8
        for (int k = 0; k < HH; k += 4) {
            f32x4 hvv = *(const f32x4*)(hp + k);
            f32x4 wv = *(const f32x4*)(wp + k);
            s.x = fmaf(hvv.x, wv.x, s.x); s.y = fmaf(hvv.y, wv.y, s.y);
            s.z = fmaf(hvv.z, wv.z, s.z); s.w = fmaf(hvv.w, wv.w, s.w);
        }
        glds[bb * 33 + rr] = gx_cur + xctx + ((s.x + s.y) + (s.z + s.w));
        __syncthreads();   // glds ready; hlds free for restage
        if (tid < 64) {
            const int bb2 = tid >> 3, uu2 = tid & 7;
            const int bg2 = bg * 8 + bb2;
            float gi = glds[bb2 * 33 + 0 + uu2];
            float gf = glds[bb2 * 33 + 8 + uu2];
            float gg = glds[bb2 * 33 + 16 + uu2];
            float go = glds[bb2 * 33 + 24 + uu2];
            float c = sigf(gf) * clds[tid] + sigf(gi) * tanh_(gg);
            float h = sigf(go) * tanh_(c);
            clds[tid] = c;
            out[((size_t)bg2 * TT + t) * HH + u0 + uu2] = h;  // plain (kernel-boundary readers)
            unsigned long long pv = ((unsigned long long)(unsigned int)(tag_base + t + 1) << 32)
                                  | (unsigned long long)__float_as_uint(h);
            __hip_atomic_store(ring + ((size_t)t * BB + bg2) * HH + u0 + uu2, pv,
                               __ATOMIC_RELAXED, __HIP_MEMORY_SCOPE_AGENT);
            if (cT && t == TT - 1) cT[(size_t)bg2 * HH + u0 + uu2] = c;
        }
        if (t + 1 < TT) {
            // poll-stage h(t) for next step's dot: data carries its own validity
            const unsigned int want = (unsigned int)(tag_base + t + 1);
            const unsigned long long* rp = ring + ((size_t)t * BB + bg * 8 + hrow) * HH + hc0;
            unsigned long long v[16];
            bool ok;
            do {
                ok = true;
                #pragma unroll
                for (int j = 0; j < 16; j++)
                    v[j] = __hip_atomic_load(rp + 32 * j, __ATOMIC_RELAXED,
                                             __HIP_MEMORY_SCOPE_AGENT);
                #pragma unroll
                for (int j = 0; j < 16; j++)
                    ok &= ((unsigned int)(v[j] >> 32) == want);
            } while (!ok);
            float* hd = &hlds[hrow * 516 + hc0];
            #pragma unroll
            for (int j = 0; j < 16; j++)
                hd[32 * j] = __uint_as_float((unsigned int)v[j]);
        }
        gx_cur = gx_nxt;
    }
}

// ---------------- final projection: bf16 MFMA GEMM, C = A*B^T + bias ----------------
// A: hid bf16 [M][K]. B: W2 fp32 [N][K] (converted to bf16 during staging). C fp32.
__global__ __launch_bounds__(256) void gemm_bf16(
    const ushort_t* __restrict__ A,
    const float* __restrict__ B,
    const float* __restrict__ bias,
    float* __restrict__ C, int M, int N, int K)
{
    __shared__ ushort_t As[128 * 72];
    __shared__ ushort_t Bs[128 * 72];
    const int tid = threadIdx.x;
    const int bm = blockIdx.x * 128, bn = blockIdx.y * 128;
    const int lane = tid & 63, wave = tid >> 6;
    const int wm = (wave & 1) * 64, wn = (wave >> 1) * 64;
    const int lr = lane & 15, lk = (lane >> 4) * 8;
    const int srow = tid >> 3, sch = tid & 7;
    f32x4 acc[4][4] = {};

    for (int k0 = 0; k0 < K; k0 += 64) {
        #pragma unroll
        for (int rr = 0; rr < 4; rr++) {
            int row = srow + rr * 32;
            const ushort_t* as = A + (size_t)(bm + row) * K + k0 + sch * 8;
            *(int4*)&As[row * 72 + sch * 8] = *(const int4*)as;
            const float* bs = B + (size_t)(bn + row) * K + k0 + sch * 8;
            float4 f0 = *(const float4*)bs;
            float4 f1 = *(const float4*)(bs + 4);
            int4 pk;
            pk.x = (int)f2bf(f0.x) | ((int)f2bf(f0.y) << 16);
            pk.y = (int)f2bf(f0.z) | ((int)f2bf(f0.w) << 16);
            pk.z = (int)f2bf(f1.x) | ((int)f2bf(f1.y) << 16);
            pk.w = (int)f2bf(f1.z) | ((int)f2bf(f1.w) << 16);
            *(int4*)&Bs[row * 72 + sch * 8] = pk;
        }
        __syncthreads();
        #pragma unroll
        for (int k2 = 0; k2 < 64; k2 += 32) {
            bf16x8 a[4], bfr[4];
            #pragma unroll
            for (int i = 0; i < 4; i++)
                a[i] = *(const bf16x8*)&As[(wm + i * 16 + lr) * 72 + k2 + lk];
            #pragma unroll
            for (int j = 0; j < 4; j++)
                bfr[j] = *(const bf16x8*)&Bs[(wn + j * 16 + lr) * 72 + k2 + lk];
            #pragma unroll
            for (int i = 0; i < 4; i++)
                #pragma unroll
                for (int j = 0; j < 4; j++)
                    acc[i][j] = __builtin_amdgcn_mfma_f32_16x16x32_bf16(a[i], bfr[j], acc[i][j], 0, 0, 0);
        }
        __syncthreads();
    }
    const int r0 = (lane >> 4) * 4;
    #pragma unroll
    for (int j = 0; j < 4; j++) {
        int col = bn + wn + j * 16 + lr;
        float bv = bias[col];
        #pragma unroll
        for (int i = 0; i < 4; i++) {
            int row = bm + wm + i * 16 + r0;
            #pragma unroll
            for (int q = 0; q < 4; q++)
                C[(size_t)(row + q) * N + col] = acc[i][j][q] + bv;
        }
    }
}

extern "C" void kernel_launch(void* const* d_in, const int* in_sizes, int n_in,
                              void* d_out, int out_size, void* d_ws, size_t ws_size,
                              hipStream_t stream) {
    const int*   src      = (const int*)d_in[0];
    const int*   tgt      = (const int*)d_in[1];
    const float* enc_emb  = (const float*)d_in[2];
    const float* dec_emb  = (const float*)d_in[3];
    const float* eWih0    = (const float*)d_in[4];
    const float* eWhh0    = (const float*)d_in[5];
    const float* eb0      = (const float*)d_in[6];
    const float* eWih1    = (const float*)d_in[7];
    const float* eWhh1    = (const float*)d_in[8];
    const float* eb1      = (const float*)d_in[9];
    const float* dWih0    = (const float*)d_in[10];
    const float* dWhh0    = (const float*)d_in[11];
    const float* db0      = (const float*)d_in[12];
    const float* dWih1    = (const float*)d_in[13];
    const float* dWhh1    = (const float*)d_in[14];
    const float* db1      = (const float*)d_in[15];
    const float* pW1      = (const float*)d_in[16];
    const float* pb1      = (const float*)d_in[17];
    const float* pW2      = (const float*)d_in[18];
    const float* pb2      = (const float*)d_in[19];
    float* out = (float*)d_out;

    // workspace carve (small persistent buffers)
    float* fws   = (float*)d_ws;
    float* zeros = fws;                        // 512 f (padded to 1024)
    float* cT0   = fws + 2048;                 // 16384 f
    float* cT1   = cT0 + 16384;
    float* ctx   = cT1 + 16384;
    float* ctxW  = ctx + 16384;                // 65536 f
    ushort_t* hid = (ushort_t*)(ctxW + 65536); // 2048*512 bf16

    // d_out scratch (all dead before final projection writes everything)
    float* G0  = out;                 // 2048*2048 gate buffers
    float* G1  = G0 + 4194304;
    float* G2  = G1 + 4194304;
    float* G3  = G2 + 4194304;
    float* xe  = G3 + 4194304;        // 2048*256
    float* xd  = xe + 524288;
    float* e0  = xd + 524288;         // 2048*512
    float* e1  = e0 + 1048576;
    float* d0  = e1 + 1048576;
    float* d1v = d0 + 1048576;
    unsigned long long* ring = (unsigned long long*)(d1v + 1048576); // [64][32][512] tagged h

    zero_init<<<1, 256, 0, stream>>>(zeros);
    gather_rows<<<2048, 64, 0, stream>>>(src, enc_emb, xe);
    gather_rows<<<2048, 64, 0, stream>>>(tgt, dec_emb, xd);

    // encoder layer 0
    gemm_f32<<<dim3(32, 32), 256, 0, stream>>>(xe, 256, eWih0, 256, eb0, G0, 2048, 2048, 2048, 256, 0);
    lstm_scan<<<256, 256, 0, stream>>>(G0, nullptr, eWhh0, zeros, 0, zeros, 0, e0, cT0, ring, 0);
    // encoder layer 1
    gemm_f32<<<dim3(32, 32), 256, 0, stream>>>(e0, 512, eWih1, 512, eb1, G1, 2048, 2048, 2048, 512, 0);
    lstm_scan<<<256, 256, 0, stream>>>(G1, nullptr, eWhh1, zeros, 0, zeros, 0, e1, cT1, ring, 64);
    // context
    mean_ctx<<<64, 256, 0, stream>>>(e1, ctx);
    // decoder layer 0: gates = xd*Wih[:, :256]^T + b + ctx*Wih[:, 256:]^T (added in scan)
    gemm_f32<<<dim3(32, 32), 256, 0, stream>>>(xd, 256, dWih0, 768, db0, G2, 2048, 2048, 2048, 256, 0);
    gemm_f32<<<dim3(32, 1), 256, 0, stream>>>(ctx, 512, dWih0 + 256, 768, nullptr, ctxW, 2048, 32, 2048, 512, 0);
    lstm_scan<<<256, 256, 0, stream>>>(G2, ctxW, dWhh0, e0 + 63 * 512, 64 * 512, cT0, 512, d0, nullptr, ring, 128);
    // decoder layer 1
    gemm_f32<<<dim3(32, 32), 256, 0, stream>>>(d0, 512, dWih1, 512, db1, G3, 2048, 2048, 2048, 512, 0);
    lstm_scan<<<256, 256, 0, stream>>>(G3, nullptr, dWhh1, e1 + 63 * 512, 64 * 512, cT1, 512, d1v, nullptr, ring, 192);
    // projection: hid = tanh(d1*W1^T + b1) stored bf16; logits = hid*W2^T + b2 (MFMA)
    gemm_f32<<<dim3(8, 32), 256, 0, stream>>>(d1v, 512, pW1, 512, pb1, hid, 512, 2048, 512, 512, 2);
    gemm_bf16<<<dim3(16, 250), 256, 0, stream>>>(hid, pW2, pb2, out, 2048, 32000, 512);
}